// Round 1
// baseline (156.923 us; speedup 1.0000x reference)
//
#include <hip/hip_runtime.h>
#include <hip/hip_bf16.h>

// Problem constants (from reference): IN_F=OUT_F=512, K=8, B*S=8192
#define IN_FEAT 512
#define OUT_FEAT 512
#define NTOK 8192
#define KDIM 4096   // IN_FEAT * 8 effective features (basis_0 folded into bias)

#define BM 128
#define BN 64
#define BK 64       // 8 inputs * 8 features per K-iter
#define LDA 72      // +8 bf16 pad -> conflict-free ds_read_b128
#define LDB 72

typedef short bf16x8 __attribute__((ext_vector_type(8)));
typedef float f32x4 __attribute__((ext_vector_type(4)));

static __device__ inline short f2bf(float f) {
    union { float f; unsigned u; } v; v.f = f;
    unsigned u = v.u;
    u += 0x7fffu + ((u >> 16) & 1u);   // RNE
    return (short)(u >> 16);
}

// Prep: W[o, i*8+0] = scale_base[o,i]; W[o, i*8+f] = scale_spline[o,i]*coeff[o,i,f] (f=1..7)
// bias[o] = sum_i base_bias[o,i] + scale_spline[o,i]*coeff[o,i,0]
__global__ __launch_bounds__(256) void kan_prep(
    const float* __restrict__ coeff, const float* __restrict__ scale_base,
    const float* __restrict__ scale_spline, const float* __restrict__ base_bias,
    short* __restrict__ Wb, float* __restrict__ bias)
{
    int o = blockIdx.x;
    int tid = threadIdx.x;
    float local = 0.f;
#pragma unroll
    for (int rep = 0; rep < 2; ++rep) {
        int i = tid + rep * 256;
        size_t oi = (size_t)o * IN_FEAT + i;
        const float4* c4 = (const float4*)(coeff + oi * 8);
        float4 ca = c4[0], cb = c4[1];
        float ss = scale_spline[oi];
        float sb = scale_base[oi];
        local += base_bias[oi] + ss * ca.x;
        bf16x8 w;
        w[0] = f2bf(sb);
        w[1] = f2bf(ss * ca.y); w[2] = f2bf(ss * ca.z); w[3] = f2bf(ss * ca.w);
        w[4] = f2bf(ss * cb.x); w[5] = f2bf(ss * cb.y); w[6] = f2bf(ss * cb.z);
        w[7] = f2bf(ss * cb.w);
        *(bf16x8*)(Wb + (size_t)o * KDIM + (size_t)i * 8) = w;
    }
    __shared__ float red[4];
    for (int off = 32; off > 0; off >>= 1) local += __shfl_down(local, off, 64);
    int lane = tid & 63, wv = tid >> 6;
    if (lane == 0) red[wv] = local;
    __syncthreads();
    if (tid == 0) bias[o] = red[0] + red[1] + red[2] + red[3];
}

// Fused GEMM: A (computed on the fly from x) [8192 x 4096] bf16  x  W^T -> out [8192 x 512] fp32
__global__ __launch_bounds__(256) void kan_gemm(
    const float* __restrict__ x, const short* __restrict__ Wb,
    const float* __restrict__ bias, float* __restrict__ out)
{
    __shared__ __align__(16) short As[BM * LDA];
    __shared__ __align__(16) short Bs[BN * LDB];

    int tid = threadIdx.x;
    int mb = blockIdx.x >> 3;   // 64 m-blocks
    int nb = blockIdx.x & 7;    // 8 n-blocks
    int m0 = mb * BM, o0 = nb * BN;

    int lane = tid & 63, wv = tid >> 6;
    int wm = wv >> 1, wn = wv & 1;          // wave tile: 64x32
    int qd = lane >> 4, ln15 = lane & 15;

    f32x4 acc[4][2];
#pragma unroll
    for (int a = 0; a < 4; ++a)
#pragma unroll
        for (int b = 0; b < 2; ++b) acc[a][b] = (f32x4)0.f;

    int n_local = tid >> 1;     // 0..127
    int half = tid & 1;         // which float4 of the 8-input chunk
    const float4* xrow = (const float4*)(x + (size_t)(m0 + n_local) * IN_FEAT);

    for (int it = 0; it < IN_FEAT / 8; ++it) {   // 64 K-iterations
        // ---- A-tile generation: 8 inputs -> 64 bf16 features per row ----
        float4 xv = xrow[it * 2 + half];
        float xs[4] = {xv.x, xv.y, xv.z, xv.w};
#pragma unroll
        for (int ii = 0; ii < 4; ++ii) {
            float xc = fminf(fmaxf(xs[ii], -1.f), 1.f);
            float base = xc / (1.f + __expf(-xc));    // silu
            bf16x8 fr;
            fr[0] = f2bf(base);
            float t = xc;
            fr[1] = f2bf(t);
#pragma unroll
            for (int f = 2; f < 8; ++f) { t = 2.f * xc * t - 1.f; fr[f] = f2bf(t); }
            *(bf16x8*)&As[n_local * LDA + half * 32 + ii * 8] = fr;
        }
        // ---- B-tile stage: 64 rows x 64 features ----
#pragma unroll
        for (int rep = 0; rep < 2; ++rep) {
            int c = tid + rep * 256;
            int row = c >> 3, cc = c & 7;
            bf16x8 wfrag = *(const bf16x8*)(Wb + (size_t)(o0 + row) * KDIM + it * BK + cc * 8);
            *(bf16x8*)&Bs[row * LDB + cc * 8] = wfrag;
        }
        __syncthreads();
        // ---- MFMA: wave computes 64x32 via 4x2 frags, 2 k-steps of 32 ----
#pragma unroll
        for (int kq = 0; kq < 2; ++kq) {
            bf16x8 af[4], bfr[2];
#pragma unroll
            for (int fm = 0; fm < 4; ++fm)
                af[fm] = *(const bf16x8*)&As[(wm * 64 + fm * 16 + ln15) * LDA + kq * 32 + qd * 8];
#pragma unroll
            for (int fn = 0; fn < 2; ++fn)
                bfr[fn] = *(const bf16x8*)&Bs[(wn * 32 + fn * 16 + ln15) * LDB + kq * 32 + qd * 8];
#pragma unroll
            for (int fm = 0; fm < 4; ++fm)
#pragma unroll
                for (int fn = 0; fn < 2; ++fn)
                    acc[fm][fn] = __builtin_amdgcn_mfma_f32_16x16x32_bf16(
                        af[fm], bfr[fn], acc[fm][fn], 0, 0, 0);
        }
        __syncthreads();
    }

    // ---- epilogue: C/D layout row=qd*4+reg, col=ln15; add folded bias ----
#pragma unroll
    for (int fn = 0; fn < 2; ++fn) {
        int o = o0 + wn * 32 + fn * 16 + ln15;
        float bv = bias[o];
#pragma unroll
        for (int fm = 0; fm < 4; ++fm) {
            int r0 = m0 + wm * 64 + fm * 16 + qd * 4;
#pragma unroll
            for (int r = 0; r < 4; ++r)
                out[(size_t)(r0 + r) * OUT_FEAT + o] = acc[fm][fn][r] + bv;
        }
    }
}

extern "C" void kernel_launch(void* const* d_in, const int* in_sizes, int n_in,
                              void* d_out, int out_size, void* d_ws, size_t ws_size,
                              hipStream_t stream) {
    const float* x            = (const float*)d_in[0];
    const float* coeff        = (const float*)d_in[1];
    const float* scale_base   = (const float*)d_in[2];
    const float* scale_spline = (const float*)d_in[3];
    const float* base_bias    = (const float*)d_in[4];
    float* out = (float*)d_out;

    short* Wb   = (short*)d_ws;                                   // 512*4096*2 = 4 MB
    float* bias = (float*)((char*)d_ws + (size_t)OUT_FEAT * KDIM * 2);

    kan_prep<<<OUT_FEAT, 256, 0, stream>>>(coeff, scale_base, scale_spline, base_bias, Wb, bias);
    kan_gemm<<<(NTOK / BM) * (OUT_FEAT / BN), 256, 0, stream>>>(x, Wb, bias, out);
}